// Round 8
// baseline (241.502 us; speedup 1.0000x reference)
//
#include <hip/hip_runtime.h>
#include <hip/hip_bf16.h>

typedef unsigned short u16;
typedef __attribute__((ext_vector_type(8))) short short8;
typedef __attribute__((ext_vector_type(4))) float floatx4;
typedef __attribute__((ext_vector_type(2))) float f32x2;

#define N_NODES 50000
#define N_EDGES 400000
#define ET      450000   // edges + self loops
#define F_IN    128
#define C1      256      // H*HID
#define HID     64
#define OUTC    64
#define SLOPE   0.2f
#define LIN1_BLOCKS 782  // ceil(50000/64)
#define LOG2E   1.44269504089f

#if __has_builtin(__builtin_amdgcn_exp2f)
#define EXP2(x) __builtin_amdgcn_exp2f(x)
#else
#define EXP2(x) __expf((x) * 0.69314718056f)
#endif

__device__ __forceinline__ float bf2f(u16 v) {
    return __uint_as_float(((unsigned)v) << 16);
}
__device__ __forceinline__ float bflo(unsigned u) { return __uint_as_float(u << 16); }
__device__ __forceinline__ float bfhi(unsigned u) { return __uint_as_float(u & 0xffff0000u); }
__device__ __forceinline__ u16 f2bf(float f) {   // round-to-nearest-even
    unsigned u = __float_as_uint(f);
    return (u16)((u + 0x7fffu + ((u >> 16) & 1u)) >> 16);
}
__device__ __forceinline__ f32x2 up2(unsigned u) {
    f32x2 r; r.x = bflo(u); r.y = bfhi(u); return r;
}
template<int CTRL>
__device__ __forceinline__ float dpp_add(float x) {
    return x + __int_as_float(__builtin_amdgcn_update_dpp(
        0, __float_as_int(x), CTRL, 0xF, 0xF, true));
}
__device__ __forceinline__ float red16(float p) {
    p = dpp_add<0xB1>(p);
    p = dpp_add<0x4E>(p);
    p = dpp_add<0x141>(p);
    p = dpp_add<0x140>(p);
    return p;
}
// paired 16-lane reduction: two independent scalars packed in f32x2
template<int CTRL>
__device__ __forceinline__ f32x2 dpp_add2(f32x2 x) {
    f32x2 o;
    o.x = __int_as_float(__builtin_amdgcn_update_dpp(
        0, __float_as_int(x.x), CTRL, 0xF, 0xF, true));
    o.y = __int_as_float(__builtin_amdgcn_update_dpp(
        0, __float_as_int(x.y), CTRL, 0xF, 0xF, true));
    return x + o;
}
__device__ __forceinline__ f32x2 red16x2(f32x2 p) {
    p = dpp_add2<0xB1>(p);
    p = dpp_add2<0x4E>(p);
    p = dpp_add2<0x141>(p);
    p = dpp_add2<0x140>(p);
    return p;
}
__device__ __forceinline__ bool detect_f32(const unsigned* __restrict__ xw) {
    unsigned w = xw[threadIdx.x & 63];
    unsigned aexp = (w >> 7) & 0xFFu;
    unsigned long long b = __ballot(aexp >= 170u || aexp <= 40u);
    return __popcll(b) >= 16;
}

// ---------------- fused param convert + hist zero ---------------------------
// Weights are written in MFMA-fragment-packed order so the linear kernels can
// stream B-fragments from global with fully-coalesced lane*16B loads:
//   lin1: wt[side*32768 + ((ch*4+cf)*4+kk)*512 + lane*8 + j]
//   lin2: wt2[side*16384 + (cf*8+kk)*512 + lane*8 + j]
__global__ __launch_bounds__(256) void convert_all_kernel(
    const unsigned* __restrict__ xw,
    const void* wl1, const void* wr1, const void* wl2, const void* wr2,
    const void* s0, const void* s1, const void* s2, const void* s3,
    const void* s4, const void* s5, const void* s6, const void* s7,
    u16* __restrict__ wt, u16* __restrict__ prm, int* __restrict__ hist)
{
    if (blockIdx.x >= 385) {
        int idx = (blockIdx.x - 385) * 256 + threadIdx.x;
        if (idx < N_NODES) hist[idx] = 0;
        return;
    }
    bool f32m = detect_f32(xw);
    if (blockIdx.x == 384) {
        for (int t = threadIdx.x; t < 1280; t += 256) {
            const void* src; int local;
            if      (t < 256)  { src = s0; local = t; }
            else if (t < 512)  { src = s1; local = t - 256; }
            else if (t < 768)  { src = s2; local = t - 512; }
            else if (t < 1024) { src = s3; local = t - 768; }
            else if (t < 1088) { src = s4; local = t - 1024; }
            else if (t < 1152) { src = s5; local = t - 1088; }
            else if (t < 1216) { src = s6; local = t - 1152; }
            else               { src = s7; local = t - 1216; }
            prm[t] = f32m ? f2bf(((const float*)src)[local]) : ((const u16*)src)[local];
        }
        return;
    }
    int t = blockIdx.x * 256 + threadIdx.x;   // 98304 total
    const void* src; int local, k, n, dst;
    if (t < 32768) {          // Wl1 (128x256), element (k,n) at k*256+n
        src = wl1; local = t; k = local >> 8; n = local & 255;
        int ch = n >> 6, cf = (n >> 4) & 3, l16 = n & 15;
        int kk = k >> 5, quad = (k >> 3) & 3, j = k & 7;
        dst = 0 + ((ch * 4 + cf) * 4 + kk) * 512 + (quad * 16 + l16) * 8 + j;
    } else if (t < 65536) {   // Wr1
        src = wr1; local = t - 32768; k = local >> 8; n = local & 255;
        int ch = n >> 6, cf = (n >> 4) & 3, l16 = n & 15;
        int kk = k >> 5, quad = (k >> 3) & 3, j = k & 7;
        dst = 32768 + ((ch * 4 + cf) * 4 + kk) * 512 + (quad * 16 + l16) * 8 + j;
    } else if (t < 81920) {   // Wl2 (256x64), element (k,n) at k*64+n
        src = wl2; local = t - 65536; k = local >> 6; n = local & 63;
        int cf = n >> 4, l16 = n & 15;
        int kk = k >> 5, quad = (k >> 3) & 3, j = k & 7;
        dst = 65536 + (cf * 8 + kk) * 512 + (quad * 16 + l16) * 8 + j;
    } else {                  // Wr2
        src = wr2; local = t - 81920; k = local >> 6; n = local & 63;
        int cf = n >> 4, l16 = n & 15;
        int kk = k >> 5, quad = (k >> 3) & 3, j = k & 7;
        dst = 81920 + (cf * 8 + kk) * 512 + (quad * 16 + l16) * 8 + j;
    }
    u16 v = f32m ? f2bf(((const float*)src)[local]) : ((const u16*)src)[local];
    wt[dst] = v;
}

// ---------------- CSR scan (phases) ----------------
__global__ __launch_bounds__(256) void scan1_kernel(const int* __restrict__ hist,
                                                    int* __restrict__ rowptr,
                                                    int* __restrict__ bsum)
{
    int t = threadIdx.x;
    int i = blockIdx.x * 256 + t;
    int v = (i < N_NODES) ? hist[i] : 0;
    __shared__ int sd[256];
    sd[t] = v;
    __syncthreads();
    #pragma unroll
    for (int ofs = 1; ofs < 256; ofs <<= 1) {
        int u = (t >= ofs) ? sd[t - ofs] : 0;
        __syncthreads();
        sd[t] += u;
        __syncthreads();
    }
    if (i < N_NODES) rowptr[i] = sd[t] - v;
    if (t == 255) bsum[blockIdx.x] = sd[255];
}

__global__ __launch_bounds__(256) void scan3_kernel(int* __restrict__ rowptr,
                                                    const int* __restrict__ bsum,
                                                    int* __restrict__ off)
{
    int t = threadIdx.x;
    int v = (t < (int)blockIdx.x) ? bsum[t] : 0;   // blockIdx.x <= 195
    __shared__ int sd[256];
    sd[t] = v;
    __syncthreads();
    #pragma unroll
    for (int ofs = 1; ofs < 256; ofs <<= 1) {
        int u = (t >= ofs) ? sd[t - ofs] : 0;
        __syncthreads();
        sd[t] += u;
        __syncthreads();
    }
    int boff = sd[255];
    int i = blockIdx.x * 256 + t;
    if (i < N_NODES) {
        int r = rowptr[i] + boff;
        rowptr[i] = r;
        off[i] = r;
    }
}

__global__ __launch_bounds__(256) void scatter_kernel(const int* __restrict__ ei,
                                                      int* __restrict__ off,
                                                      int* __restrict__ src_csr)
{
    int t = blockIdx.x * 256 + threadIdx.x;
    if (t >= ET) return;
    int s, d;
    if (t < N_EDGES) { s = ei[t]; d = ei[N_EDGES + t]; } else { s = d = t - N_EDGES; }
    int pos = atomicAdd(&off[d], 1);
    src_csr[pos] = s;
}

// ---------------- fused lin1 + hist: X in LDS, W streamed from global -------
__global__ __launch_bounds__(256) void lin1_hist_kernel(
    const u16* __restrict__ X, const u16* __restrict__ Wp,   // Wp: packed [2][32768]
    const u16* __restrict__ bl, const u16* __restrict__ br,
    u16* __restrict__ Yl, u16* __restrict__ Yr, int nrows,
    const int* __restrict__ ei, int* __restrict__ hist)
{
    constexpr int K = 128, N = 256, LS = K + 8;
    __shared__ __align__(16) u16 sX[64 * LS];

    if (blockIdx.x >= LIN1_BLOCKS) {
        int t = (blockIdx.x - LIN1_BLOCKS) * 256 + threadIdx.x;
        if (t < ET) {
            int d = (t < N_EDGES) ? ei[N_EDGES + t] : t - N_EDGES;
            atomicAdd(&hist[d], 1);
        }
        return;
    }

    const bool f32m = detect_f32((const unsigned*)X);
    const float* X32 = (const float*)X;
    const int row0 = blockIdx.x * 64;
    const int wave = threadIdx.x >> 6, lane = threadIdx.x & 63;
    const int quad = lane >> 4, l16 = lane & 15;

    for (int i = threadIdx.x * 8; i < 64 * K; i += 2048) {
        int r = i >> 7, c = i & 127;
        int gr = row0 + r;
        u16* dst = &sX[r * LS + c];
        if (f32m) {
            float4 v0 = make_float4(0.f, 0.f, 0.f, 0.f), v1 = v0;
            if (gr < nrows) {
                v0 = *(const float4*)&X32[(size_t)gr * K + c];
                v1 = *(const float4*)&X32[(size_t)gr * K + c + 4];
            }
            ushort4 p0, p1;
            p0.x = f2bf(v0.x); p0.y = f2bf(v0.y); p0.z = f2bf(v0.z); p0.w = f2bf(v0.w);
            p1.x = f2bf(v1.x); p1.y = f2bf(v1.y); p1.z = f2bf(v1.z); p1.w = f2bf(v1.w);
            *(ushort4*)dst = p0;
            *(ushort4*)(dst + 4) = p1;
        } else {
            uint4 v = {0u, 0u, 0u, 0u};
            if (gr < nrows) v = *(const uint4*)&X[(size_t)gr * K + c];
            *(uint4*)dst = v;
        }
    }
    __syncthreads();

    // preload A-fragments once (reused across all 8 col rounds)
    short8 a[4];
    #pragma unroll
    for (int kk = 0; kk < 4; ++kk)
        a[kk] = *(const short8*)&sX[(wave * 16 + l16) * LS + kk * 32 + quad * 8];

    const u16* wlane = Wp + lane * 8;   // per-lane base into packed fragments
    for (int side = 0; side < 2; ++side) {
        const u16* bias  = side ? br : bl;
        u16* Y = side ? Yr : Yl;
        const u16* wside = wlane + side * 32768;
        for (int ch = 0; ch < 4; ++ch) {
            const u16* wch = wside + ch * 8192;
            short8 b[16];
            #pragma unroll
            for (int cf = 0; cf < 4; ++cf)
                #pragma unroll
                for (int kk = 0; kk < 4; ++kk)
                    b[cf * 4 + kk] = *(const short8*)&wch[(cf * 4 + kk) * 512];
            floatx4 acc0 = {0.f, 0.f, 0.f, 0.f}, acc1 = acc0, acc2 = acc0, acc3 = acc0;
            #pragma unroll
            for (int kk = 0; kk < 4; ++kk) {
                acc0 = __builtin_amdgcn_mfma_f32_16x16x32_bf16(a[kk], b[kk],      acc0, 0, 0, 0);
                acc1 = __builtin_amdgcn_mfma_f32_16x16x32_bf16(a[kk], b[4 + kk],  acc1, 0, 0, 0);
                acc2 = __builtin_amdgcn_mfma_f32_16x16x32_bf16(a[kk], b[8 + kk],  acc2, 0, 0, 0);
                acc3 = __builtin_amdgcn_mfma_f32_16x16x32_bf16(a[kk], b[12 + kk], acc3, 0, 0, 0);
            }
            const int rbase = row0 + wave * 16 + quad * 4;
            #pragma unroll
            for (int cf = 0; cf < 4; ++cf) {
                const floatx4 av = (cf == 0) ? acc0 : (cf == 1) ? acc1 : (cf == 2) ? acc2 : acc3;
                const int col = ch * 64 + cf * 16 + l16;
                const float bv = bf2f(bias[col]);
                #pragma unroll
                for (int r = 0; r < 4; ++r) {
                    int row = rbase + r;
                    if (row < nrows) Y[(size_t)row * N + col] = f2bf(av[r] + bv);
                }
            }
        }
    }
}

// ---------------- layer-2 linear: X in LDS, W streamed from global ----------
__global__ __launch_bounds__(256) void lin2_fused_kernel(
    const u16* __restrict__ X, const u16* __restrict__ Wp,   // Wp: packed [2][16384]
    const u16* __restrict__ bl, const u16* __restrict__ br,
    u16* __restrict__ Yl, u16* __restrict__ Yr, int nrows)
{
    constexpr int K = 256, N = 64, LS = K + 8;
    __shared__ __align__(16) u16 sX[64 * LS];
    const int row0 = blockIdx.x * 64;
    const int wave = threadIdx.x >> 6, lane = threadIdx.x & 63;
    const int quad = lane >> 4, l16 = lane & 15;

    for (int i = threadIdx.x * 8; i < 64 * K; i += 2048) {
        int r = i >> 8, c = i & 255;
        int gr = row0 + r;
        uint4 v = {0u, 0u, 0u, 0u};
        if (gr < nrows) v = *(const uint4*)&X[(size_t)gr * K + c];
        *(uint4*)&sX[r * LS + c] = v;
    }
    __syncthreads();

    short8 a[8];
    #pragma unroll
    for (int kk = 0; kk < 8; ++kk)
        a[kk] = *(const short8*)&sX[(wave * 16 + l16) * LS + kk * 32 + quad * 8];

    const u16* wlane = Wp + lane * 8;
    for (int side = 0; side < 2; ++side) {
        const u16* bias  = side ? br : bl;
        u16* Y = side ? Yr : Yl;
        const u16* wside = wlane + side * 16384;
        #pragma unroll
        for (int cf = 0; cf < 4; ++cf) {
            short8 b[8];
            #pragma unroll
            for (int kk = 0; kk < 8; ++kk)
                b[kk] = *(const short8*)&wside[(cf * 8 + kk) * 512];
            floatx4 acc = {0.f, 0.f, 0.f, 0.f};
            #pragma unroll
            for (int kk = 0; kk < 8; ++kk)
                acc = __builtin_amdgcn_mfma_f32_16x16x32_bf16(a[kk], b[kk], acc, 0, 0, 0);
            const int rbase = row0 + wave * 16 + quad * 4;
            const int col = cf * 16 + l16;
            const float bv = bf2f(bias[col]);
            #pragma unroll
            for (int r = 0; r < 4; ++r) {
                int row = rbase + r;
                if (row < nrows) Y[(size_t)row * N + col] = f2bf(acc[r] + bv);
            }
        }
    }
}

// ---------------- layer 1 fused per-node GATv2 (4 heads x 64 ch) ------------
// 2-quad-deep software pipeline: 8 gathers (4 KB) in flight per wave.
// Peeled maskless main loop; wave-uniform defer-rescale; scalar CSR loads.
__global__ __launch_bounds__(64, 6) void node1_kernel(
    const u16* __restrict__ xl, const u16* __restrict__ xr,
    const int* __restrict__ rowptr, const int* __restrict__ hist,
    const int* __restrict__ src_csr, const u16* __restrict__ att,
    const u16* __restrict__ bias, u16* __restrict__ hout)
{
    const int d = blockIdx.x;
    const int l = threadIdx.x;           // 0..63
    const int start = __builtin_amdgcn_readfirstlane(rowptr[d]);
    const int deg = __builtin_amdgcn_readfirstlane(hist[d]);
    const int dm1 = deg - 1;
    const u16* __restrict__ xlp = xl + l * 4;   // per-lane column base

    uint2 auv = *(const uint2*)&att[l * 4];
    const f32x2 atA = up2(auv.x) * LOG2E, atB = up2(auv.y) * LOG2E;
    uint2 ruv = *(const uint2*)&xr[(size_t)d * C1 + l * 4];
    const f32x2 rA = up2(ruv.x), rB = up2(ruv.y);

    float m = -1e30f, la = 0.f;
    f32x2 accA = {0.f, 0.f}, accB = {0.f, 0.f};

    // prefetch quads 0 and 1 (clamped; deg >= 1 always: self loop)
    int s0 = __builtin_amdgcn_readfirstlane(src_csr[start]);
    int s1 = __builtin_amdgcn_readfirstlane(src_csr[start + min(1, dm1)]);
    int s2 = __builtin_amdgcn_readfirstlane(src_csr[start + min(2, dm1)]);
    int s3 = __builtin_amdgcn_readfirstlane(src_csr[start + min(3, dm1)]);
    uint2 u0 = *(const uint2*)&xlp[(size_t)s0 * C1];
    uint2 u1 = *(const uint2*)&xlp[(size_t)s1 * C1];
    uint2 u2 = *(const uint2*)&xlp[(size_t)s2 * C1];
    uint2 u3 = *(const uint2*)&xlp[(size_t)s3 * C1];
    int t0 = __builtin_amdgcn_readfirstlane(src_csr[start + min(4, dm1)]);
    int t1 = __builtin_amdgcn_readfirstlane(src_csr[start + min(5, dm1)]);
    int t2 = __builtin_amdgcn_readfirstlane(src_csr[start + min(6, dm1)]);
    int t3 = __builtin_amdgcn_readfirstlane(src_csr[start + min(7, dm1)]);
    uint2 v0 = *(const uint2*)&xlp[(size_t)t0 * C1];
    uint2 v1q = *(const uint2*)&xlp[(size_t)t1 * C1];
    uint2 v2q = *(const uint2*)&xlp[(size_t)t2 * C1];
    uint2 v3q = *(const uint2*)&xlp[(size_t)t3 * C1];

    int j = 0;
    for (; j + 4 <= deg; j += 4) {       // full quads: maskless
        const uint2 c0 = u0, c1 = u1, c2 = u2, c3 = u3;
        // shift pipeline: B -> A
        u0 = v0; u1 = v1q; u2 = v2q; u3 = v3q;
        const int jn = j + 8;
        if (jn < deg) {   // issue quad j+8's loads under current compute
            int q0 = __builtin_amdgcn_readfirstlane(src_csr[start + jn]);
            int q1 = __builtin_amdgcn_readfirstlane(src_csr[start + min(jn + 1, dm1)]);
            int q2 = __builtin_amdgcn_readfirstlane(src_csr[start + min(jn + 2, dm1)]);
            int q3 = __builtin_amdgcn_readfirstlane(src_csr[start + min(jn + 3, dm1)]);
            v0  = *(const uint2*)&xlp[(size_t)q0 * C1];
            v1q = *(const uint2*)&xlp[(size_t)q1 * C1];
            v2q = *(const uint2*)&xlp[(size_t)q2 * C1];
            v3q = *(const uint2*)&xlp[(size_t)q3 * C1];
        }
        f32x2 x0A = up2(c0.x), x0B = up2(c0.y);
        f32x2 x1A = up2(c1.x), x1B = up2(c1.y);
        f32x2 x2A = up2(c2.x), x2B = up2(c2.y);
        f32x2 x3A = up2(c3.x), x3B = up2(c3.y);
        f32x2 t, pv;
        t = x0A + rA; t = __builtin_elementwise_max(t, t * SLOPE); pv  = t * atA;
        t = x0B + rB; t = __builtin_elementwise_max(t, t * SLOPE); pv += t * atB;
        float p0 = pv.x + pv.y;
        t = x1A + rA; t = __builtin_elementwise_max(t, t * SLOPE); pv  = t * atA;
        t = x1B + rB; t = __builtin_elementwise_max(t, t * SLOPE); pv += t * atB;
        float p1 = pv.x + pv.y;
        t = x2A + rA; t = __builtin_elementwise_max(t, t * SLOPE); pv  = t * atA;
        t = x2B + rB; t = __builtin_elementwise_max(t, t * SLOPE); pv += t * atB;
        float p2 = pv.x + pv.y;
        t = x3A + rA; t = __builtin_elementwise_max(t, t * SLOPE); pv  = t * atA;
        t = x3B + rB; t = __builtin_elementwise_max(t, t * SLOPE); pv += t * atB;
        float p3 = pv.x + pv.y;
        f32x2 P01 = {p0, p1}, P23 = {p2, p3};
        P01 = red16x2(P01);
        P23 = red16x2(P23);
        p0 = P01.x; p1 = P01.y; p2 = P23.x; p3 = P23.y;
        float pm = fmaxf(fmaxf(p0, p1), fmaxf(p2, p3));
        if (__any(pm > m)) {             // wave-uniform defer-rescale
            float mn = fmaxf(m, pm);
            float sc = EXP2(m - mn);
            la *= sc; accA *= sc; accB *= sc;
            m = mn;
        }
        float w0 = EXP2(p0 - m);
        float w1 = EXP2(p1 - m);
        float w2 = EXP2(p2 - m);
        float w3 = EXP2(p3 - m);
        la += w0 + w1 + w2 + w3;
        accA += x0A * w0 + x1A * w1 + x2A * w2 + x3A * w3;
        accB += x0B * w0 + x1B * w1 + x2B * w2 + x3B * w3;
    }
    if (j < deg) {                        // tail: 1..3 edges (in u0..u2, clamped)
        const bool v1 = j + 1 < deg, v2 = j + 2 < deg;
        f32x2 x0A = up2(u0.x), x0B = up2(u0.y);
        f32x2 x1A = up2(u1.x), x1B = up2(u1.y);
        f32x2 x2A = up2(u2.x), x2B = up2(u2.y);
        f32x2 t, pv;
        t = x0A + rA; t = __builtin_elementwise_max(t, t * SLOPE); pv  = t * atA;
        t = x0B + rB; t = __builtin_elementwise_max(t, t * SLOPE); pv += t * atB;
        float p0 = pv.x + pv.y;
        t = x1A + rA; t = __builtin_elementwise_max(t, t * SLOPE); pv  = t * atA;
        t = x1B + rB; t = __builtin_elementwise_max(t, t * SLOPE); pv += t * atB;
        float p1 = pv.x + pv.y;
        t = x2A + rA; t = __builtin_elementwise_max(t, t * SLOPE); pv  = t * atA;
        t = x2B + rB; t = __builtin_elementwise_max(t, t * SLOPE); pv += t * atB;
        float p2 = pv.x + pv.y;
        f32x2 P01 = {p0, p1};
        P01 = red16x2(P01);
        p0 = P01.x; p1 = P01.y;
        p2 = red16(p2);
        float pm = p0;
        if (v1) pm = fmaxf(pm, p1);
        if (v2) pm = fmaxf(pm, p2);
        if (__any(pm > m)) {
            float mn = fmaxf(m, pm);
            float sc = EXP2(m - mn);
            la *= sc; accA *= sc; accB *= sc;
            m = mn;
        }
        float w0 = EXP2(p0 - m);
        float w1 = v1 ? EXP2(p1 - m) : 0.f;
        float w2 = v2 ? EXP2(p2 - m) : 0.f;
        la += w0 + w1 + w2;
        accA += x0A * w0 + x1A * w1 + x2A * w2;
        accB += x0B * w0 + x1B * w1 + x2B * w2;
    }
    const float inv = 1.f / la;
    const int c = l * 4;
    float o0 = accA.x * inv + bf2f(bias[c + 0]);
    float o1 = accA.y * inv + bf2f(bias[c + 1]);
    float o2 = accB.x * inv + bf2f(bias[c + 2]);
    float o3 = accB.y * inv + bf2f(bias[c + 3]);
    o0 = o0 > 0.f ? o0 : __expf(fminf(o0, 0.f)) - 1.f;
    o1 = o1 > 0.f ? o1 : __expf(fminf(o1, 0.f)) - 1.f;
    o2 = o2 > 0.f ? o2 : __expf(fminf(o2, 0.f)) - 1.f;
    o3 = o3 > 0.f ? o3 : __expf(fminf(o3, 0.f)) - 1.f;
    ushort4 o;
    o.x = f2bf(o0); o.y = f2bf(o1); o.z = f2bf(o2); o.w = f2bf(o3);
    *(ushort4*)&hout[(size_t)d * C1 + c] = o;
}

// ---------------- layer 2 fused per-node GATv2 (1 head x 64 ch) --------------
// 1 wave per node; 8 edges/iter (each 16-lane group handles 2 edges, scores
// share one paired red16x2); 2-deep clamped prefetch (16 edges in flight).
__global__ __launch_bounds__(64, 8) void node2_kernel(
    const u16* __restrict__ xl, const u16* __restrict__ xr,
    const int* __restrict__ rowptr, const int* __restrict__ hist,
    const int* __restrict__ src_csr, const u16* __restrict__ att,
    const u16* __restrict__ bias, void* __restrict__ outp,
    const unsigned* __restrict__ xorig)
{
    const bool f32o = detect_f32(xorig);
    const int d = blockIdx.x;
    const int l = threadIdx.x;           // 0..63
    const int start = __builtin_amdgcn_readfirstlane(rowptr[d]);
    const int deg = __builtin_amdgcn_readfirstlane(hist[d]);
    const int dm1 = deg - 1;
    const int g = l >> 4, sub = l & 15;
    const int c0 = sub * 4;
    const u16* __restrict__ xlp = xl + c0;

    uint2 auv = *(const uint2*)&att[c0];
    const f32x2 atA = up2(auv.x) * LOG2E, atB = up2(auv.y) * LOG2E;
    uint2 ruv = *(const uint2*)&xr[(size_t)d * OUTC + c0];
    const f32x2 rA = up2(ruv.x), rB = up2(ruv.y);

    float m = -1e30f, la = 0.f;
    f32x2 accA = {0.f, 0.f}, accB = {0.f, 0.f};

    // prefetch first 16 edges (2 per group x 2-deep, all clamped in-range)
    int sA0 = src_csr[start + min(g, dm1)];
    int sA1 = src_csr[start + min(g + 4, dm1)];
    uint2 uA0 = *(const uint2*)&xlp[(size_t)sA0 * OUTC];
    uint2 uA1 = *(const uint2*)&xlp[(size_t)sA1 * OUTC];
    int sB0 = src_csr[start + min(g + 8, dm1)];
    int sB1 = src_csr[start + min(g + 12, dm1)];
    uint2 uB0 = *(const uint2*)&xlp[(size_t)sB0 * OUTC];
    uint2 uB1 = *(const uint2*)&xlp[(size_t)sB1 * OUTC];

    for (int j = 0; j < deg; j += 8) {
        const bool val0 = j + g < deg, val1 = j + g + 4 < deg;
        const uint2 e0 = uA0, e1 = uA1;
        uA0 = uB0; uA1 = uB1;
        if (j + 8 < deg) {   // prefetch edges j+16..j+23 (clamped)
            int t0 = src_csr[start + min(j + 16 + g, dm1)];
            int t1 = src_csr[start + min(j + 20 + g, dm1)];
            uB0 = *(const uint2*)&xlp[(size_t)t0 * OUTC];
            uB1 = *(const uint2*)&xlp[(size_t)t1 * OUTC];
        }
        f32x2 x0A = up2(e0.x), x0B = up2(e0.y);
        f32x2 x1A = up2(e1.x), x1B = up2(e1.y);
        f32x2 t, pv;
        t = x0A + rA; t = __builtin_elementwise_max(t, t * SLOPE); pv  = t * atA;
        t = x0B + rB; t = __builtin_elementwise_max(t, t * SLOPE); pv += t * atB;
        float p0 = pv.x + pv.y;
        t = x1A + rA; t = __builtin_elementwise_max(t, t * SLOPE); pv  = t * atA;
        t = x1B + rB; t = __builtin_elementwise_max(t, t * SLOPE); pv += t * atB;
        float p1 = pv.x + pv.y;
        f32x2 P = {p0, p1};
        P = red16x2(P);
        p0 = P.x; p1 = P.y;
        float q0 = val0 ? p0 : -1e30f;
        float q1 = val1 ? p1 : -1e30f;
        float pm = fmaxf(q0, q1);
        if (__any(pm > m)) {             // wave-uniform defer-rescale
            float mn = fmaxf(m, pm);
            float sc = EXP2(m - mn);
            la *= sc; accA *= sc; accB *= sc;
            m = mn;
        }
        float w0 = val0 ? EXP2(p0 - m) : 0.f;
        float w1 = val1 ? EXP2(p1 - m) : 0.f;
        la += w0 + w1;
        accA += x0A * w0 + x1A * w1;
        accB += x0B * w0 + x1B * w1;
    }
    #pragma unroll
    for (int ofs = 16; ofs <= 32; ofs <<= 1) {
        float mo = __shfl_xor(m, ofs);
        float lo = __shfl_xor(la, ofs);
        float bax = __shfl_xor(accA.x, ofs);
        float bay = __shfl_xor(accA.y, ofs);
        float bbx = __shfl_xor(accB.x, ofs);
        float bby = __shfl_xor(accB.y, ofs);
        float mn = fmaxf(m, mo);
        float e0 = EXP2(m - mn), e1 = EXP2(mo - mn);
        la = la * e0 + lo * e1;
        accA.x = accA.x * e0 + bax * e1;
        accA.y = accA.y * e0 + bay * e1;
        accB.x = accB.x * e0 + bbx * e1;
        accB.y = accB.y * e0 + bby * e1;
        m = mn;
    }
    if (g == 0) {
        const float inv = 1.f / la;
        float v0 = accA.x * inv + bf2f(bias[c0 + 0]);
        float v1 = accA.y * inv + bf2f(bias[c0 + 1]);
        float v2 = accB.x * inv + bf2f(bias[c0 + 2]);
        float v3 = accB.y * inv + bf2f(bias[c0 + 3]);
        if (f32o) {
            float4 o = make_float4(v0, v1, v2, v3);
            *(float4*)&((float*)outp)[(size_t)d * OUTC + c0] = o;
        } else {
            ushort4 o;
            o.x = f2bf(v0); o.y = f2bf(v1); o.z = f2bf(v2); o.w = f2bf(v3);
            *(ushort4*)&((u16*)outp)[(size_t)d * OUTC + c0] = o;
        }
    }
}

extern "C" void kernel_launch(void* const* d_in, const int* in_sizes, int n_in,
                              void* d_out, int out_size, void* d_ws, size_t ws_size,
                              hipStream_t stream)
{
    const void* x  = d_in[0];
    const int*  ei = (const int*)d_in[1];

    char* ws = (char*)d_ws;
    u16* xl1     = (u16*)(ws + 0);          // 25.6 MB
    u16* xr1     = (u16*)(ws + 25600000);   // 25.6 MB
    u16* hbuf    = (u16*)(ws + 51200000);   // 25.6 MB
    u16* xl2     = (u16*)(ws + 0);          // overlay xl1 (dead after node1)
    u16* xr2     = (u16*)(ws + 6400000);
    int* hist    = (int*)(ws + 76800000);
    int* rowptr  = (int*)(ws + 77000000);
    int* off     = (int*)(ws + 77200000);
    int* src_csr = (int*)(ws + 77400000);   // 1.8 MB
    u16* prm     = (u16*)(ws + 79200064);   // 1280 u16 small params
    u16* wt      = (u16*)(ws + 79210240);   // 98304 u16 packed weights
    int* bsum    = (int*)(ws + 79410000);

    u16* bl1   = prm + 0;
    u16* br1   = prm + 256;
    u16* att1  = prm + 512;
    u16* bias1 = prm + 768;
    u16* bl2   = prm + 1024;
    u16* br2   = prm + 1088;
    u16* att2  = prm + 1152;
    u16* bias2 = prm + 1216;
    u16* wt1   = wt + 0;       // packed [2][32768]
    u16* wt2   = wt + 65536;   // packed [2][16384]

    // D1: param convert (fragment-packed weights) + hist zero
    convert_all_kernel<<<581, 256, 0, stream>>>(
        (const unsigned*)x,
        d_in[2], d_in[4], d_in[8], d_in[10],
        d_in[3], d_in[5], d_in[6], d_in[7], d_in[9], d_in[11], d_in[12], d_in[13],
        wt, prm, hist);

    // D2: lin1 (X in LDS, W streamed) + hist fused
    const int eb = (ET + 255) / 256;   // 1758 hist blocks
    lin1_hist_kernel<<<LIN1_BLOCKS + eb, 256, 0, stream>>>(
        (const u16*)x, wt1, bl1, br1, xl1, xr1, N_NODES, ei, hist);

    // D3-D5: CSR scan + scatter
    scan1_kernel<<<196, 256, 0, stream>>>(hist, rowptr, bsum);
    scan3_kernel<<<196, 256, 0, stream>>>(rowptr, bsum, off);
    scatter_kernel<<<eb, 256, 0, stream>>>(ei, off, src_csr);

    // D6-D8: node1 (2-quad pipeline), lin2, node2
    node1_kernel<<<N_NODES, 64, 0, stream>>>(xl1, xr1, rowptr, hist, src_csr, att1, bias1, hbuf);
    lin2_fused_kernel<<<(N_NODES + 63) / 64, 256, 0, stream>>>(hbuf, wt2, bl2, br2, xl2, xr2, N_NODES);
    node2_kernel<<<N_NODES, 64, 0, stream>>>(xl2, xr2, rowptr, hist, src_csr, att2, bias2, d_out,
                                             (const unsigned*)x);
}

// Round 9
// 239.822 us; speedup vs baseline: 1.0070x; 1.0070x over previous
//
#include <hip/hip_runtime.h>
#include <hip/hip_bf16.h>

typedef unsigned short u16;
typedef __attribute__((ext_vector_type(8))) short short8;
typedef __attribute__((ext_vector_type(4))) float floatx4;
typedef __attribute__((ext_vector_type(2))) float f32x2;

#define N_NODES 50000
#define N_EDGES 400000
#define ET      450000   // edges + self loops
#define F_IN    128
#define C1      256      // H*HID
#define HID     64
#define OUTC    64
#define SLOPE   0.2f
#define LIN1_WAVES 6250  // 3125 row-tiles x 2 sides, 1 wave each
#define LOG2E   1.44269504089f

#if __has_builtin(__builtin_amdgcn_exp2f)
#define EXP2(x) __builtin_amdgcn_exp2f(x)
#else
#define EXP2(x) __expf((x) * 0.69314718056f)
#endif

__device__ __forceinline__ float bf2f(u16 v) {
    return __uint_as_float(((unsigned)v) << 16);
}
__device__ __forceinline__ float bflo(unsigned u) { return __uint_as_float(u << 16); }
__device__ __forceinline__ float bfhi(unsigned u) { return __uint_as_float(u & 0xffff0000u); }
__device__ __forceinline__ u16 f2bf(float f) {   // round-to-nearest-even
    unsigned u = __float_as_uint(f);
    return (u16)((u + 0x7fffu + ((u >> 16) & 1u)) >> 16);
}
__device__ __forceinline__ f32x2 up2(unsigned u) {
    f32x2 r; r.x = bflo(u); r.y = bfhi(u); return r;
}
template<int CTRL>
__device__ __forceinline__ float dpp_add(float x) {
    return x + __int_as_float(__builtin_amdgcn_update_dpp(
        0, __float_as_int(x), CTRL, 0xF, 0xF, true));
}
__device__ __forceinline__ float red16(float p) {
    p = dpp_add<0xB1>(p);
    p = dpp_add<0x4E>(p);
    p = dpp_add<0x141>(p);
    p = dpp_add<0x140>(p);
    return p;
}
// paired 16-lane reduction: two independent scalars packed in f32x2
template<int CTRL>
__device__ __forceinline__ f32x2 dpp_add2(f32x2 x) {
    f32x2 o;
    o.x = __int_as_float(__builtin_amdgcn_update_dpp(
        0, __float_as_int(x.x), CTRL, 0xF, 0xF, true));
    o.y = __int_as_float(__builtin_amdgcn_update_dpp(
        0, __float_as_int(x.y), CTRL, 0xF, 0xF, true));
    return x + o;
}
__device__ __forceinline__ f32x2 red16x2(f32x2 p) {
    p = dpp_add2<0xB1>(p);
    p = dpp_add2<0x4E>(p);
    p = dpp_add2<0x141>(p);
    p = dpp_add2<0x140>(p);
    return p;
}
__device__ __forceinline__ bool detect_f32(const unsigned* __restrict__ xw) {
    unsigned w = xw[threadIdx.x & 63];
    unsigned aexp = (w >> 7) & 0xFFu;
    unsigned long long b = __ballot(aexp >= 170u || aexp <= 40u);
    return __popcll(b) >= 16;
}

// ---------------- fused param convert + hist zero ---------------------------
// Weights are written in MFMA-fragment-packed order so the linear kernels can
// stream B-fragments from global with fully-coalesced lane*16B loads:
//   lin1: wt[side*32768 + ((ch*4+cf)*4+kk)*512 + lane*8 + j]
//   lin2: wt2[side*16384 + (cf*8+kk)*512 + lane*8 + j]
__global__ __launch_bounds__(256) void convert_all_kernel(
    const unsigned* __restrict__ xw,
    const void* wl1, const void* wr1, const void* wl2, const void* wr2,
    const void* s0, const void* s1, const void* s2, const void* s3,
    const void* s4, const void* s5, const void* s6, const void* s7,
    u16* __restrict__ wt, u16* __restrict__ prm, int* __restrict__ hist)
{
    if (blockIdx.x >= 385) {
        int idx = (blockIdx.x - 385) * 256 + threadIdx.x;
        if (idx < N_NODES) hist[idx] = 0;
        return;
    }
    bool f32m = detect_f32(xw);
    if (blockIdx.x == 384) {
        for (int t = threadIdx.x; t < 1280; t += 256) {
            const void* src; int local;
            if      (t < 256)  { src = s0; local = t; }
            else if (t < 512)  { src = s1; local = t - 256; }
            else if (t < 768)  { src = s2; local = t - 512; }
            else if (t < 1024) { src = s3; local = t - 768; }
            else if (t < 1088) { src = s4; local = t - 1024; }
            else if (t < 1152) { src = s5; local = t - 1088; }
            else if (t < 1216) { src = s6; local = t - 1152; }
            else               { src = s7; local = t - 1216; }
            prm[t] = f32m ? f2bf(((const float*)src)[local]) : ((const u16*)src)[local];
        }
        return;
    }
    int t = blockIdx.x * 256 + threadIdx.x;   // 98304 total
    const void* src; int local, k, n, dst;
    if (t < 32768) {          // Wl1 (128x256), element (k,n) at k*256+n
        src = wl1; local = t; k = local >> 8; n = local & 255;
        int ch = n >> 6, cf = (n >> 4) & 3, l16 = n & 15;
        int kk = k >> 5, quad = (k >> 3) & 3, j = k & 7;
        dst = 0 + ((ch * 4 + cf) * 4 + kk) * 512 + (quad * 16 + l16) * 8 + j;
    } else if (t < 65536) {   // Wr1
        src = wr1; local = t - 32768; k = local >> 8; n = local & 255;
        int ch = n >> 6, cf = (n >> 4) & 3, l16 = n & 15;
        int kk = k >> 5, quad = (k >> 3) & 3, j = k & 7;
        dst = 32768 + ((ch * 4 + cf) * 4 + kk) * 512 + (quad * 16 + l16) * 8 + j;
    } else if (t < 81920) {   // Wl2 (256x64), element (k,n) at k*64+n
        src = wl2; local = t - 65536; k = local >> 6; n = local & 63;
        int cf = n >> 4, l16 = n & 15;
        int kk = k >> 5, quad = (k >> 3) & 3, j = k & 7;
        dst = 65536 + (cf * 8 + kk) * 512 + (quad * 16 + l16) * 8 + j;
    } else {                  // Wr2
        src = wr2; local = t - 81920; k = local >> 6; n = local & 63;
        int cf = n >> 4, l16 = n & 15;
        int kk = k >> 5, quad = (k >> 3) & 3, j = k & 7;
        dst = 81920 + (cf * 8 + kk) * 512 + (quad * 16 + l16) * 8 + j;
    }
    u16 v = f32m ? f2bf(((const float*)src)[local]) : ((const u16*)src)[local];
    wt[dst] = v;
}

// ---------------- CSR scan (phases) ----------------
__global__ __launch_bounds__(256) void scan1_kernel(const int* __restrict__ hist,
                                                    int* __restrict__ rowptr,
                                                    int* __restrict__ bsum)
{
    int t = threadIdx.x;
    int i = blockIdx.x * 256 + t;
    int v = (i < N_NODES) ? hist[i] : 0;
    __shared__ int sd[256];
    sd[t] = v;
    __syncthreads();
    #pragma unroll
    for (int ofs = 1; ofs < 256; ofs <<= 1) {
        int u = (t >= ofs) ? sd[t - ofs] : 0;
        __syncthreads();
        sd[t] += u;
        __syncthreads();
    }
    if (i < N_NODES) rowptr[i] = sd[t] - v;
    if (t == 255) bsum[blockIdx.x] = sd[255];
}

__global__ __launch_bounds__(256) void scan3_kernel(int* __restrict__ rowptr,
                                                    const int* __restrict__ bsum,
                                                    int* __restrict__ off)
{
    int t = threadIdx.x;
    int v = (t < (int)blockIdx.x) ? bsum[t] : 0;   // blockIdx.x <= 195
    __shared__ int sd[256];
    sd[t] = v;
    __syncthreads();
    #pragma unroll
    for (int ofs = 1; ofs < 256; ofs <<= 1) {
        int u = (t >= ofs) ? sd[t - ofs] : 0;
        __syncthreads();
        sd[t] += u;
        __syncthreads();
    }
    int boff = sd[255];
    int i = blockIdx.x * 256 + t;
    if (i < N_NODES) {
        int r = rowptr[i] + boff;
        rowptr[i] = r;
        off[i] = r;
    }
}

__global__ __launch_bounds__(256) void scatter_kernel(const int* __restrict__ ei,
                                                      int* __restrict__ off,
                                                      int* __restrict__ src_csr)
{
    int t = blockIdx.x * 256 + threadIdx.x;
    if (t >= ET) return;
    int s, d;
    if (t < N_EDGES) { s = ei[t]; d = ei[N_EDGES + t]; } else { s = d = t - N_EDGES; }
    int pos = atomicAdd(&off[d], 1);
    src_csr[pos] = s;
}

// ---------------- lin1 + hist: 1 wave = 16 rows x 1 side, no LDS/barriers ---
// A-frags straight from global (16B/lane, k-contiguous); W packed (R8-verified
// layout) so B-frags are lane*16B coalesced bursts, L2-resident.
__global__ __launch_bounds__(64, 4) void lin1_hist_kernel(
    const u16* __restrict__ X, const u16* __restrict__ Wp,   // Wp: packed [2][32768]
    const u16* __restrict__ bl, const u16* __restrict__ br,
    u16* __restrict__ Yl, u16* __restrict__ Yr,
    const int* __restrict__ ei, int* __restrict__ hist)
{
    if (blockIdx.x >= LIN1_WAVES) {
        int t = (blockIdx.x - LIN1_WAVES) * 64 + threadIdx.x;
        if (t < ET) {
            int d = (t < N_EDGES) ? ei[N_EDGES + t] : t - N_EDGES;
            atomicAdd(&hist[d], 1);
        }
        return;
    }

    const int lane = threadIdx.x;
    const int quad = lane >> 4, l16 = lane & 15;
    const int side = blockIdx.x & 1;
    const int row0 = (blockIdx.x >> 1) * 16;   // 3125*16 = 50000 exact
    const bool f32m = detect_f32((const unsigned*)X);

    // A-fragments: lane holds X[row0+l16][kk*32+quad*8 .. +7]
    short8 a[4];
    if (f32m) {
        const float* xrow = (const float*)X + (size_t)(row0 + l16) * F_IN;
        #pragma unroll
        for (int kk = 0; kk < 4; ++kk) {
            float4 v0 = *(const float4*)&xrow[kk * 32 + quad * 8];
            float4 v1 = *(const float4*)&xrow[kk * 32 + quad * 8 + 4];
            union { ushort4 h[2]; short8 s8; } u;
            u.h[0].x = f2bf(v0.x); u.h[0].y = f2bf(v0.y);
            u.h[0].z = f2bf(v0.z); u.h[0].w = f2bf(v0.w);
            u.h[1].x = f2bf(v1.x); u.h[1].y = f2bf(v1.y);
            u.h[1].z = f2bf(v1.z); u.h[1].w = f2bf(v1.w);
            a[kk] = u.s8;
        }
    } else {
        const u16* xrow = X + (size_t)(row0 + l16) * F_IN;
        #pragma unroll
        for (int kk = 0; kk < 4; ++kk)
            a[kk] = *(const short8*)&xrow[kk * 32 + quad * 8];
    }

    const u16* wlane = Wp + side * 32768 + lane * 8;
    const u16* bias  = side ? br : bl;
    u16* Y = side ? Yr : Yl;

    for (int ch = 0; ch < 4; ++ch) {
        const u16* wch = wlane + ch * 8192;
        short8 b[16];
        #pragma unroll
        for (int f = 0; f < 16; ++f)
            b[f] = *(const short8*)&wch[f * 512];
        floatx4 acc0 = {0.f, 0.f, 0.f, 0.f}, acc1 = acc0, acc2 = acc0, acc3 = acc0;
        #pragma unroll
        for (int kk = 0; kk < 4; ++kk) {
            acc0 = __builtin_amdgcn_mfma_f32_16x16x32_bf16(a[kk], b[kk],      acc0, 0, 0, 0);
            acc1 = __builtin_amdgcn_mfma_f32_16x16x32_bf16(a[kk], b[4 + kk],  acc1, 0, 0, 0);
            acc2 = __builtin_amdgcn_mfma_f32_16x16x32_bf16(a[kk], b[8 + kk],  acc2, 0, 0, 0);
            acc3 = __builtin_amdgcn_mfma_f32_16x16x32_bf16(a[kk], b[12 + kk], acc3, 0, 0, 0);
        }
        const int rbase = row0 + quad * 4;
        #pragma unroll
        for (int cf = 0; cf < 4; ++cf) {
            const floatx4 av = (cf == 0) ? acc0 : (cf == 1) ? acc1 : (cf == 2) ? acc2 : acc3;
            const int col = ch * 64 + cf * 16 + l16;
            const float bv = bf2f(bias[col]);
            #pragma unroll
            for (int r = 0; r < 4; ++r)
                Y[(size_t)(rbase + r) * C1 + col] = f2bf(av[r] + bv);
        }
    }
}

// ---------------- lin2: 1 wave = 16 rows x 1 side, no LDS/barriers ----------
__global__ __launch_bounds__(64, 4) void lin2_fused_kernel(
    const u16* __restrict__ X, const u16* __restrict__ Wp,   // Wp: packed [2][16384]
    const u16* __restrict__ bl, const u16* __restrict__ br,
    u16* __restrict__ Yl, u16* __restrict__ Yr)
{
    const int lane = threadIdx.x;
    const int quad = lane >> 4, l16 = lane & 15;
    const int side = blockIdx.x & 1;
    const int row0 = (blockIdx.x >> 1) * 16;

    const u16* xrow = X + (size_t)(row0 + l16) * C1;
    short8 a[8];
    #pragma unroll
    for (int kk = 0; kk < 8; ++kk)
        a[kk] = *(const short8*)&xrow[kk * 32 + quad * 8];

    const u16* wlane = Wp + side * 16384 + lane * 8;
    const u16* bias  = side ? br : bl;
    u16* Y = side ? Yr : Yl;

    #pragma unroll
    for (int cf = 0; cf < 4; ++cf) {
        short8 b[8];
        #pragma unroll
        for (int kk = 0; kk < 8; ++kk)
            b[kk] = *(const short8*)&wlane[(cf * 8 + kk) * 512];
        floatx4 acc = {0.f, 0.f, 0.f, 0.f};
        #pragma unroll
        for (int kk = 0; kk < 8; ++kk)
            acc = __builtin_amdgcn_mfma_f32_16x16x32_bf16(a[kk], b[kk], acc, 0, 0, 0);
        const int rbase = row0 + quad * 4;
        const int col = cf * 16 + l16;
        const float bv = bf2f(bias[col]);
        #pragma unroll
        for (int r = 0; r < 4; ++r)
            Y[(size_t)(rbase + r) * OUTC + col] = f2bf(acc[r] + bv);
    }
}

// ---------------- layer 1 fused per-node GATv2 (4 heads x 64 ch) ------------
// 2-quad-deep software pipeline; wave-uniform defer-rescale; scalar CSR loads.
__global__ __launch_bounds__(64, 6) void node1_kernel(
    const u16* __restrict__ xl, const u16* __restrict__ xr,
    const int* __restrict__ rowptr, const int* __restrict__ hist,
    const int* __restrict__ src_csr, const u16* __restrict__ att,
    const u16* __restrict__ bias, u16* __restrict__ hout)
{
    const int d = blockIdx.x;
    const int l = threadIdx.x;           // 0..63
    const int start = __builtin_amdgcn_readfirstlane(rowptr[d]);
    const int deg = __builtin_amdgcn_readfirstlane(hist[d]);
    const int dm1 = deg - 1;
    const u16* __restrict__ xlp = xl + l * 4;   // per-lane column base

    uint2 auv = *(const uint2*)&att[l * 4];
    const f32x2 atA = up2(auv.x) * LOG2E, atB = up2(auv.y) * LOG2E;
    uint2 ruv = *(const uint2*)&xr[(size_t)d * C1 + l * 4];
    const f32x2 rA = up2(ruv.x), rB = up2(ruv.y);

    float m = -1e30f, la = 0.f;
    f32x2 accA = {0.f, 0.f}, accB = {0.f, 0.f};

    // prefetch quads 0 and 1 (clamped; deg >= 1 always: self loop)
    int s0 = __builtin_amdgcn_readfirstlane(src_csr[start]);
    int s1 = __builtin_amdgcn_readfirstlane(src_csr[start + min(1, dm1)]);
    int s2 = __builtin_amdgcn_readfirstlane(src_csr[start + min(2, dm1)]);
    int s3 = __builtin_amdgcn_readfirstlane(src_csr[start + min(3, dm1)]);
    uint2 u0 = *(const uint2*)&xlp[(size_t)s0 * C1];
    uint2 u1 = *(const uint2*)&xlp[(size_t)s1 * C1];
    uint2 u2 = *(const uint2*)&xlp[(size_t)s2 * C1];
    uint2 u3 = *(const uint2*)&xlp[(size_t)s3 * C1];
    int t0 = __builtin_amdgcn_readfirstlane(src_csr[start + min(4, dm1)]);
    int t1 = __builtin_amdgcn_readfirstlane(src_csr[start + min(5, dm1)]);
    int t2 = __builtin_amdgcn_readfirstlane(src_csr[start + min(6, dm1)]);
    int t3 = __builtin_amdgcn_readfirstlane(src_csr[start + min(7, dm1)]);
    uint2 v0 = *(const uint2*)&xlp[(size_t)t0 * C1];
    uint2 v1q = *(const uint2*)&xlp[(size_t)t1 * C1];
    uint2 v2q = *(const uint2*)&xlp[(size_t)t2 * C1];
    uint2 v3q = *(const uint2*)&xlp[(size_t)t3 * C1];

    int j = 0;
    for (; j + 4 <= deg; j += 4) {       // full quads: maskless
        const uint2 c0 = u0, c1 = u1, c2 = u2, c3 = u3;
        // shift pipeline: B -> A
        u0 = v0; u1 = v1q; u2 = v2q; u3 = v3q;
        const int jn = j + 8;
        if (jn < deg) {   // issue quad j+8's loads under current compute
            int q0 = __builtin_amdgcn_readfirstlane(src_csr[start + jn]);
            int q1 = __builtin_amdgcn_readfirstlane(src_csr[start + min(jn + 1, dm1)]);
            int q2 = __builtin_amdgcn_readfirstlane(src_csr[start + min(jn + 2, dm1)]);
            int q3 = __builtin_amdgcn_readfirstlane(src_csr[start + min(jn + 3, dm1)]);
            v0  = *(const uint2*)&xlp[(size_t)q0 * C1];
            v1q = *(const uint2*)&xlp[(size_t)q1 * C1];
            v2q = *(const uint2*)&xlp[(size_t)q2 * C1];
            v3q = *(const uint2*)&xlp[(size_t)q3 * C1];
        }
        f32x2 x0A = up2(c0.x), x0B = up2(c0.y);
        f32x2 x1A = up2(c1.x), x1B = up2(c1.y);
        f32x2 x2A = up2(c2.x), x2B = up2(c2.y);
        f32x2 x3A = up2(c3.x), x3B = up2(c3.y);
        f32x2 t, pv;
        t = x0A + rA; t = __builtin_elementwise_max(t, t * SLOPE); pv  = t * atA;
        t = x0B + rB; t = __builtin_elementwise_max(t, t * SLOPE); pv += t * atB;
        float p0 = pv.x + pv.y;
        t = x1A + rA; t = __builtin_elementwise_max(t, t * SLOPE); pv  = t * atA;
        t = x1B + rB; t = __builtin_elementwise_max(t, t * SLOPE); pv += t * atB;
        float p1 = pv.x + pv.y;
        t = x2A + rA; t = __builtin_elementwise_max(t, t * SLOPE); pv  = t * atA;
        t = x2B + rB; t = __builtin_elementwise_max(t, t * SLOPE); pv += t * atB;
        float p2 = pv.x + pv.y;
        t = x3A + rA; t = __builtin_elementwise_max(t, t * SLOPE); pv  = t * atA;
        t = x3B + rB; t = __builtin_elementwise_max(t, t * SLOPE); pv += t * atB;
        float p3 = pv.x + pv.y;
        f32x2 P01 = {p0, p1}, P23 = {p2, p3};
        P01 = red16x2(P01);
        P23 = red16x2(P23);
        p0 = P01.x; p1 = P01.y; p2 = P23.x; p3 = P23.y;
        float pm = fmaxf(fmaxf(p0, p1), fmaxf(p2, p3));
        if (__any(pm > m)) {             // wave-uniform defer-rescale
            float mn = fmaxf(m, pm);
            float sc = EXP2(m - mn);
            la *= sc; accA *= sc; accB *= sc;
            m = mn;
        }
        float w0 = EXP2(p0 - m);
        float w1 = EXP2(p1 - m);
        float w2 = EXP2(p2 - m);
        float w3 = EXP2(p3 - m);
        la += w0 + w1 + w2 + w3;
        accA += x0A * w0 + x1A * w1 + x2A * w2 + x3A * w3;
        accB += x0B * w0 + x1B * w1 + x2B * w2 + x3B * w3;
    }
    if (j < deg) {                        // tail: 1..3 edges (in u0..u2, clamped)
        const bool v1 = j + 1 < deg, v2 = j + 2 < deg;
        f32x2 x0A = up2(u0.x), x0B = up2(u0.y);
        f32x2 x1A = up2(u1.x), x1B = up2(u1.y);
        f32x2 x2A = up2(u2.x), x2B = up2(u2.y);
        f32x2 t, pv;
        t = x0A + rA; t = __builtin_elementwise_max(t, t * SLOPE); pv  = t * atA;
        t = x0B + rB; t = __builtin_elementwise_max(t, t * SLOPE); pv += t * atB;
        float p0 = pv.x + pv.y;
        t = x1A + rA; t = __builtin_elementwise_max(t, t * SLOPE); pv  = t * atA;
        t = x1B + rB; t = __builtin_elementwise_max(t, t * SLOPE); pv += t * atB;
        float p1 = pv.x + pv.y;
        t = x2A + rA; t = __builtin_elementwise_max(t, t * SLOPE); pv  = t * atA;
        t = x2B + rB; t = __builtin_elementwise_max(t, t * SLOPE); pv += t * atB;
        float p2 = pv.x + pv.y;
        f32x2 P01 = {p0, p1};
        P01 = red16x2(P01);
        p0 = P01.x; p1 = P01.y;
        p2 = red16(p2);
        float pm = p0;
        if (v1) pm = fmaxf(pm, p1);
        if (v2) pm = fmaxf(pm, p2);
        if (__any(pm > m)) {
            float mn = fmaxf(m, pm);
            float sc = EXP2(m - mn);
            la *= sc; accA *= sc; accB *= sc;
            m = mn;
        }
        float w0 = EXP2(p0 - m);
        float w1 = v1 ? EXP2(p1 - m) : 0.f;
        float w2 = v2 ? EXP2(p2 - m) : 0.f;
        la += w0 + w1 + w2;
        accA += x0A * w0 + x1A * w1 + x2A * w2;
        accB += x0B * w0 + x1B * w1 + x2B * w2;
    }
    const float inv = 1.f / la;
    const int c = l * 4;
    float o0 = accA.x * inv + bf2f(bias[c + 0]);
    float o1 = accA.y * inv + bf2f(bias[c + 1]);
    float o2 = accB.x * inv + bf2f(bias[c + 2]);
    float o3 = accB.y * inv + bf2f(bias[c + 3]);
    o0 = o0 > 0.f ? o0 : __expf(fminf(o0, 0.f)) - 1.f;
    o1 = o1 > 0.f ? o1 : __expf(fminf(o1, 0.f)) - 1.f;
    o2 = o2 > 0.f ? o2 : __expf(fminf(o2, 0.f)) - 1.f;
    o3 = o3 > 0.f ? o3 : __expf(fminf(o3, 0.f)) - 1.f;
    ushort4 o;
    o.x = f2bf(o0); o.y = f2bf(o1); o.z = f2bf(o2); o.w = f2bf(o3);
    *(ushort4*)&hout[(size_t)d * C1 + c] = o;
}

// ---------------- layer 2 fused per-node GATv2 (1 head x 64 ch) --------------
// 1 wave per node; 8 edges/iter (each 16-lane group handles 2 edges, scores
// share one paired red16x2); 2-deep clamped prefetch (16 edges in flight).
__global__ __launch_bounds__(64, 8) void node2_kernel(
    const u16* __restrict__ xl, const u16* __restrict__ xr,
    const int* __restrict__ rowptr, const int* __restrict__ hist,
    const int* __restrict__ src_csr, const u16* __restrict__ att,
    const u16* __restrict__ bias, void* __restrict__ outp,
    const unsigned* __restrict__ xorig)
{
    const bool f32o = detect_f32(xorig);
    const int d = blockIdx.x;
    const int l = threadIdx.x;           // 0..63
    const int start = __builtin_amdgcn_readfirstlane(rowptr[d]);
    const int deg = __builtin_amdgcn_readfirstlane(hist[d]);
    const int dm1 = deg - 1;
    const int g = l >> 4, sub = l & 15;
    const int c0 = sub * 4;
    const u16* __restrict__ xlp = xl + c0;

    uint2 auv = *(const uint2*)&att[c0];
    const f32x2 atA = up2(auv.x) * LOG2E, atB = up2(auv.y) * LOG2E;
    uint2 ruv = *(const uint2*)&xr[(size_t)d * OUTC + c0];
    const f32x2 rA = up2(ruv.x), rB = up2(ruv.y);

    float m = -1e30f, la = 0.f;
    f32x2 accA = {0.f, 0.f}, accB = {0.f, 0.f};

    // prefetch first 16 edges (2 per group x 2-deep, all clamped in-range)
    int sA0 = src_csr[start + min(g, dm1)];
    int sA1 = src_csr[start + min(g + 4, dm1)];
    uint2 uA0 = *(const uint2*)&xlp[(size_t)sA0 * OUTC];
    uint2 uA1 = *(const uint2*)&xlp[(size_t)sA1 * OUTC];
    int sB0 = src_csr[start + min(g + 8, dm1)];
    int sB1 = src_csr[start + min(g + 12, dm1)];
    uint2 uB0 = *(const uint2*)&xlp[(size_t)sB0 * OUTC];
    uint2 uB1 = *(const uint2*)&xlp[(size_t)sB1 * OUTC];

    for (int j = 0; j < deg; j += 8) {
        const bool val0 = j + g < deg, val1 = j + g + 4 < deg;
        const uint2 e0 = uA0, e1 = uA1;
        uA0 = uB0; uA1 = uB1;
        if (j + 8 < deg) {   // prefetch edges j+16..j+23 (clamped)
            int t0 = src_csr[start + min(j + 16 + g, dm1)];
            int t1 = src_csr[start + min(j + 20 + g, dm1)];
            uB0 = *(const uint2*)&xlp[(size_t)t0 * OUTC];
            uB1 = *(const uint2*)&xlp[(size_t)t1 * OUTC];
        }
        f32x2 x0A = up2(e0.x), x0B = up2(e0.y);
        f32x2 x1A = up2(e1.x), x1B = up2(e1.y);
        f32x2 t, pv;
        t = x0A + rA; t = __builtin_elementwise_max(t, t * SLOPE); pv  = t * atA;
        t = x0B + rB; t = __builtin_elementwise_max(t, t * SLOPE); pv += t * atB;
        float p0 = pv.x + pv.y;
        t = x1A + rA; t = __builtin_elementwise_max(t, t * SLOPE); pv  = t * atA;
        t = x1B + rB; t = __builtin_elementwise_max(t, t * SLOPE); pv += t * atB;
        float p1 = pv.x + pv.y;
        f32x2 P = {p0, p1};
        P = red16x2(P);
        p0 = P.x; p1 = P.y;
        float q0 = val0 ? p0 : -1e30f;
        float q1 = val1 ? p1 : -1e30f;
        float pm = fmaxf(q0, q1);
        if (__any(pm > m)) {             // wave-uniform defer-rescale
            float mn = fmaxf(m, pm);
            float sc = EXP2(m - mn);
            la *= sc; accA *= sc; accB *= sc;
            m = mn;
        }
        float w0 = val0 ? EXP2(p0 - m) : 0.f;
        float w1 = val1 ? EXP2(p1 - m) : 0.f;
        la += w0 + w1;
        accA += x0A * w0 + x1A * w1;
        accB += x0B * w0 + x1B * w1;
    }
    #pragma unroll
    for (int ofs = 16; ofs <= 32; ofs <<= 1) {
        float mo = __shfl_xor(m, ofs);
        float lo = __shfl_xor(la, ofs);
        float bax = __shfl_xor(accA.x, ofs);
        float bay = __shfl_xor(accA.y, ofs);
        float bbx = __shfl_xor(accB.x, ofs);
        float bby = __shfl_xor(accB.y, ofs);
        float mn = fmaxf(m, mo);
        float e0 = EXP2(m - mn), e1 = EXP2(mo - mn);
        la = la * e0 + lo * e1;
        accA.x = accA.x * e0 + bax * e1;
        accA.y = accA.y * e0 + bay * e1;
        accB.x = accB.x * e0 + bbx * e1;
        accB.y = accB.y * e0 + bby * e1;
        m = mn;
    }
    if (g == 0) {
        const float inv = 1.f / la;
        float v0 = accA.x * inv + bf2f(bias[c0 + 0]);
        float v1 = accA.y * inv + bf2f(bias[c0 + 1]);
        float v2 = accB.x * inv + bf2f(bias[c0 + 2]);
        float v3 = accB.y * inv + bf2f(bias[c0 + 3]);
        if (f32o) {
            float4 o = make_float4(v0, v1, v2, v3);
            *(float4*)&((float*)outp)[(size_t)d * OUTC + c0] = o;
        } else {
            ushort4 o;
            o.x = f2bf(v0); o.y = f2bf(v1); o.z = f2bf(v2); o.w = f2bf(v3);
            *(ushort4*)&((u16*)outp)[(size_t)d * OUTC + c0] = o;
        }
    }
}

extern "C" void kernel_launch(void* const* d_in, const int* in_sizes, int n_in,
                              void* d_out, int out_size, void* d_ws, size_t ws_size,
                              hipStream_t stream)
{
    const void* x  = d_in[0];
    const int*  ei = (const int*)d_in[1];

    char* ws = (char*)d_ws;
    u16* xl1     = (u16*)(ws + 0);          // 25.6 MB
    u16* xr1     = (u16*)(ws + 25600000);   // 25.6 MB
    u16* hbuf    = (u16*)(ws + 51200000);   // 25.6 MB
    u16* xl2     = (u16*)(ws + 0);          // overlay xl1 (dead after node1)
    u16* xr2     = (u16*)(ws + 6400000);
    int* hist    = (int*)(ws + 76800000);
    int* rowptr  = (int*)(ws + 77000000);
    int* off     = (int*)(ws + 77200000);
    int* src_csr = (int*)(ws + 77400000);   // 1.8 MB
    u16* prm     = (u16*)(ws + 79200064);   // 1280 u16 small params
    u16* wt      = (u16*)(ws + 79210240);   // 98304 u16 packed weights
    int* bsum    = (int*)(ws + 79410000);

    u16* bl1   = prm + 0;
    u16* br1   = prm + 256;
    u16* att1  = prm + 512;
    u16* bias1 = prm + 768;
    u16* bl2   = prm + 1024;
    u16* br2   = prm + 1088;
    u16* att2  = prm + 1152;
    u16* bias2 = prm + 1216;
    u16* wt1   = wt + 0;       // packed [2][32768]
    u16* wt2   = wt + 65536;   // packed [2][16384]

    // D1: param convert (fragment-packed weights) + hist zero
    convert_all_kernel<<<581, 256, 0, stream>>>(
        (const unsigned*)x,
        d_in[2], d_in[4], d_in[8], d_in[10],
        d_in[3], d_in[5], d_in[6], d_in[7], d_in[9], d_in[11], d_in[12], d_in[13],
        wt, prm, hist);

    // D2: lin1 (6250 one-wave GEMM blocks) + hist fused (64-thr blocks)
    const int eb = (ET + 63) / 64;   // 7032 hist blocks
    lin1_hist_kernel<<<LIN1_WAVES + eb, 64, 0, stream>>>(
        (const u16*)x, wt1, bl1, br1, xl1, xr1, ei, hist);

    // D3-D5: CSR scan + scatter
    scan1_kernel<<<196, 256, 0, stream>>>(hist, rowptr, bsum);
    scan3_kernel<<<196, 256, 0, stream>>>(rowptr, bsum, off);
    scatter_kernel<<<(ET + 255) / 256, 256, 0, stream>>>(ei, off, src_csr);

    // D6-D8: node1, lin2 (6250 one-wave blocks), node2
    node1_kernel<<<N_NODES, 64, 0, stream>>>(xl1, xr1, rowptr, hist, src_csr, att1, bias1, hbuf);
    lin2_fused_kernel<<<LIN1_WAVES, 64, 0, stream>>>(hbuf, wt2, bl2, br2, xl2, xr2);
    node2_kernel<<<N_NODES, 64, 0, stream>>>(xl2, xr2, rowptr, hist, src_csr, att2, bias2, d_out,
                                             (const unsigned*)x);
}